// Round 1
// baseline (1107.242 us; speedup 1.0000x reference)
//
#include <hip/hip_runtime.h>
#include <hip/hip_bf16.h>
#include <math.h>

#define NE_N 50000
#define NM_N 50000
#define NEDGE 500000

// ---------------- GEMM: C[M,128] = A[M,128] @ W[128,128] (+bias)(+relu) ----
__global__ __launch_bounds__(256) void gemm128_k(const float* __restrict__ A,
                                                 const float* __restrict__ W,
                                                 const float* __restrict__ bias,
                                                 float* __restrict__ C,
                                                 int M, int act) {
  __shared__ float X[64][132];
  const int tid = threadIdx.x;
  const int row0 = blockIdx.x * 64;
#pragma unroll
  for (int i = 0; i < 8; ++i) {
    int q = tid + i * 256;
    int r = q >> 5;
    int k4 = (q & 31) << 2;
    float4 v = make_float4(0.f, 0.f, 0.f, 0.f);
    if (row0 + r < M) v = *(const float4*)&A[(size_t)(row0 + r) * 128 + k4];
    *(float4*)&X[r][k4] = v;
  }
  __syncthreads();
  const int cg = tid & 15, rq = tid >> 4;
  const int c0 = cg * 8;
  float acc[4][8];
#pragma unroll
  for (int s = 0; s < 4; ++s)
#pragma unroll
    for (int j = 0; j < 8; ++j) acc[s][j] = 0.f;

#pragma unroll 4
  for (int k = 0; k < 128; ++k) {
    float xv[4] = {X[rq][k], X[rq + 16][k], X[rq + 32][k], X[rq + 48][k]};
    float4 w0 = *(const float4*)&W[k * 128 + c0];
    float4 w1 = *(const float4*)&W[k * 128 + c0 + 4];
    float wv[8] = {w0.x, w0.y, w0.z, w0.w, w1.x, w1.y, w1.z, w1.w};
#pragma unroll
    for (int s = 0; s < 4; ++s)
#pragma unroll
      for (int j = 0; j < 8; ++j) acc[s][j] = fmaf(xv[s], wv[j], acc[s][j]);
  }
#pragma unroll
  for (int s = 0; s < 4; ++s) {
    int r = row0 + rq + 16 * s;
    if (r >= M) continue;
    float o[8];
#pragma unroll
    for (int j = 0; j < 8; ++j) {
      float v = acc[s][j] + (bias ? bias[c0 + j] : 0.f);
      if (act == 1) v = fmaxf(v, 0.f);
      o[j] = v;
    }
    *(float4*)&C[(size_t)r * 128 + c0] = make_float4(o[0], o[1], o[2], o[3]);
    *(float4*)&C[(size_t)r * 128 + c0 + 4] = make_float4(o[4], o[5], o[6], o[7]);
  }
}

// ------------- V[k,h] = sum_d W[k, h*32+d] * a[h*32+d]  (fold attn vector) --
__global__ void vfold_k(const float* __restrict__ W, const float* __restrict__ a,
                        float* __restrict__ V) {
  int t = threadIdx.x;  // 512 threads
  int k = t >> 2, h = t & 3;
  float s = 0.f;
#pragma unroll
  for (int d = 0; d < 32; ++d) s += W[k * 128 + h * 32 + d] * a[h * 32 + d];
  V[k * 4 + h] = s;
}

// ------------- al[n,h] = sum_k X[n,k] * V[k,h]  (one wave per node) --------
__global__ __launch_bounds__(256) void alproj_k(const float* __restrict__ X,
                                                const float* __restrict__ V,
                                                float* __restrict__ al, int N) {
  int lane = threadIdx.x & 63;
  int n = (blockIdx.x * 256 + threadIdx.x) >> 6;
  if (n >= N) return;
  float x0 = X[(size_t)n * 128 + lane];
  float x1 = X[(size_t)n * 128 + 64 + lane];
  float p[4];
#pragma unroll
  for (int h = 0; h < 4; ++h)
    p[h] = x0 * V[lane * 4 + h] + x1 * V[(64 + lane) * 4 + h];
  for (int off = 32; off > 0; off >>= 1) {
#pragma unroll
    for (int h = 0; h < 4; ++h) p[h] += __shfl_xor(p[h], off, 64);
  }
  if (lane == 0) {
#pragma unroll
    for (int h = 0; h < 4; ++h) al[(size_t)n * 4 + h] = p[h];
  }
}

// ------------- counting sort of edges by dst -------------------------------
__global__ void hist_k(const int* __restrict__ dst, int* __restrict__ cnt, int E) {
  int e = blockIdx.x * blockDim.x + threadIdx.x;
  if (e < E) atomicAdd(&cnt[dst[e]], 1);
}

__global__ __launch_bounds__(1024) void scan_k(const int* __restrict__ cnt,
                                               int* __restrict__ offs, int n) {
  __shared__ int buf[1024];
  __shared__ int carry;
  int tid = threadIdx.x;
  if (tid == 0) carry = 0;
  __syncthreads();
  for (int base = 0; base < n; base += 1024) {
    int v = (base + tid < n) ? cnt[base + tid] : 0;
    buf[tid] = v;
    __syncthreads();
    for (int off = 1; off < 1024; off <<= 1) {
      int t = (tid >= off) ? buf[tid - off] : 0;
      __syncthreads();
      buf[tid] += t;
      __syncthreads();
    }
    if (base + tid < n) offs[base + tid] = carry + buf[tid] - v;  // exclusive
    __syncthreads();
    if (tid == 0) carry += buf[1023];
    __syncthreads();
  }
  if (tid == 0) offs[n] = carry;
}

__global__ void scatter_k(const int* __restrict__ src, const int* __restrict__ dst,
                          const int* __restrict__ offs, int* __restrict__ cur,
                          int* __restrict__ ssrc, int E) {
  int e = blockIdx.x * blockDim.x + threadIdx.x;
  if (e < E) {
    int d = dst[e];
    int pos = offs[d] + atomicAdd(&cur[d], 1);
    ssrc[pos] = src[e];
  }
}

// ------------- per-dst online-softmax aggregation (+bias, +ELU) ------------
__global__ __launch_bounds__(256) void gat_agg_k(const float* __restrict__ hs,
    const float* __restrict__ als, const float* __restrict__ ald,
    const int* __restrict__ offs, const int* __restrict__ ssrc,
    const float* __restrict__ bias, float* __restrict__ out, int Ndst) {
  int lane = threadIdx.x & 63;
  int n = (blockIdx.x * 256 + threadIdx.x) >> 6;
  if (n >= Ndst) return;
  int h = lane >> 4;  // 2 elems/lane -> head = (2*lane)/32
  float ad = ald[(size_t)n * 4 + h];
  int i0 = offs[n], i1 = offs[n + 1];
  float m = -INFINITY, den = 0.f, a0 = 0.f, a1 = 0.f;
  for (int i = i0; i < i1; ++i) {
    int s = ssrc[i];
    float e = als[(size_t)s * 4 + h] + ad;
    e = (e > 0.f) ? e : 0.2f * e;  // leaky_relu 0.2
    float2 hv = *(const float2*)&hs[(size_t)s * 128 + 2 * lane];
    float mn = fmaxf(m, e);
    float sc = __expf(m - mn);   // exp(-inf)=0 on first edge
    float p = __expf(e - mn);
    a0 = a0 * sc + p * hv.x;
    a1 = a1 * sc + p * hv.y;
    den = den * sc + p;
    m = mn;
  }
  float inv = 1.f / (den + 1e-16f);
  float r0 = a0 * inv + bias[2 * lane];
  float r1 = a1 * inv + bias[2 * lane + 1];
  r0 = (r0 > 0.f) ? r0 : expm1f(r0);  // ELU
  r1 = (r1 > 0.f) ? r1 : expm1f(r1);
  *(float2*)&out[(size_t)n * 128 + 2 * lane] = make_float2(r0, r1);
}

// ------------- fused regressor tail: pred = (relu(h1@W2+b2))@W3+b3 ---------
__global__ __launch_bounds__(256) void reg_tail_k(const float* __restrict__ h1,
    const float* __restrict__ W2, const float* __restrict__ b2,
    const float* __restrict__ W3, const float* __restrict__ b3,
    float* __restrict__ pred, int M) {
  int lane = threadIdx.x & 63;
  int r = (blockIdx.x * 256 + threadIdx.x) >> 6;
  if (r >= M) return;
  float acc = b2[lane];
#pragma unroll 4
  for (int k = 0; k < 128; ++k)
    acc = fmaf(h1[(size_t)r * 128 + k], W2[k * 64 + lane], acc);
  acc = fmaxf(acc, 0.f);
  float v = acc * W3[lane];
  for (int off = 32; off > 0; off >>= 1) v += __shfl_xor(v, off, 64);
  if (lane == 0) pred[r] = v + b3[0];
}

extern "C" void kernel_launch(void* const* d_in, const int* in_sizes, int n_in,
                              void* d_out, int out_size, void* d_ws, size_t ws_size,
                              hipStream_t stream) {
  const float* x_exp   = (const float*)d_in[0];
  const float* x_mat   = (const float*)d_in[1];
  const int*   ei_em   = (const int*)d_in[2];
  const int*   ei_me   = (const int*)d_in[3];
  const float* Win_exp = (const float*)d_in[4];
  const float* bin_exp = (const float*)d_in[5];
  const float* Win_mat = (const float*)d_in[6];
  const float* bin_mat = (const float*)d_in[7];
  const float* Wsrc_em = (const float*)d_in[8];
  const float* Wdst_em = (const float*)d_in[9];
  const float* asrc_em = (const float*)d_in[10];
  const float* adst_em = (const float*)d_in[11];
  const float* b_em    = (const float*)d_in[12];
  const float* Wsrc_me = (const float*)d_in[13];
  const float* Wdst_me = (const float*)d_in[14];
  const float* asrc_me = (const float*)d_in[15];
  const float* adst_me = (const float*)d_in[16];
  const float* b_me    = (const float*)d_in[17];
  const float* Wr1     = (const float*)d_in[18];
  const float* br1     = (const float*)d_in[19];
  const float* Wr2     = (const float*)d_in[20];
  const float* br2     = (const float*)d_in[21];
  const float* Wr3     = (const float*)d_in[22];
  const float* br3     = (const float*)d_in[23];

  float* pred = (float*)d_out;
  float* heO  = pred + NE_N;                  // he buffer (A), becomes final he
  float* hmO  = heO + (size_t)NE_N * 128;     // hm buffer (D), becomes final hm

  float* ws   = (float*)d_ws;
  float* B    = ws;                            // 6.4M floats
  float* Cb   = B + (size_t)NM_N * 128;        // 6.4M floats
  float* als  = Cb + (size_t)NE_N * 128;
  float* ald  = als + 200000;
  float* als2 = ald + 200000;
  float* ald2 = als2 + 200000;
  float* Vs   = ald2 + 200000;
  float* Vd   = Vs + 512;
  float* Vs2  = Vd + 512;
  float* Vd2  = Vs2 + 512;
  int* offs_em = (int*)(Vd2 + 512);
  int* cur_em  = offs_em + (NM_N + 1);
  int* ssrc_em = cur_em + NM_N;
  int* offs_me = ssrc_em + NEDGE;
  int* cur_me  = offs_me + (NE_N + 1);
  int* ssrc_me = cur_me + NE_N;

  const int* se = ei_em;          // exp src
  const int* de = ei_em + NEDGE;  // mat dst
  const int* sm = ei_me;          // mat src
  const int* dm = ei_me + NEDGE;  // exp dst

  const int gE = (NEDGE + 255) / 256;
  const int gRow = (NE_N + 63) / 64;
  const int gWave = (NE_N + 3) / 4;

  // ---- counting sort of both edge types by dst ----
  hipMemsetAsync(cur_em, 0, NM_N * sizeof(int), stream);
  hist_k<<<gE, 256, 0, stream>>>(de, cur_em, NEDGE);
  scan_k<<<1, 1024, 0, stream>>>(cur_em, offs_em, NM_N);
  hipMemsetAsync(cur_em, 0, NM_N * sizeof(int), stream);
  scatter_k<<<gE, 256, 0, stream>>>(se, de, offs_em, cur_em, ssrc_em, NEDGE);

  hipMemsetAsync(cur_me, 0, NE_N * sizeof(int), stream);
  hist_k<<<gE, 256, 0, stream>>>(dm, cur_me, NEDGE);
  scan_k<<<1, 1024, 0, stream>>>(cur_me, offs_me, NE_N);
  hipMemsetAsync(cur_me, 0, NE_N * sizeof(int), stream);
  scatter_k<<<gE, 256, 0, stream>>>(sm, dm, offs_me, cur_me, ssrc_me, NEDGE);

  // ---- input projections: he0 -> heO, hm0 -> B ----
  gemm128_k<<<gRow, 256, 0, stream>>>(x_exp, Win_exp, bin_exp, heO, NE_N, 0);
  gemm128_k<<<gRow, 256, 0, stream>>>(x_mat, Win_mat, bin_mat, B, NM_N, 0);

  // ---- layer 1, conv em (src=exp heO, dst=mat B) -> hmO = elu(om) ----
  vfold_k<<<1, 512, 0, stream>>>(Wsrc_em, asrc_em, Vs);
  vfold_k<<<1, 512, 0, stream>>>(Wdst_em, adst_em, Vd);
  gemm128_k<<<gRow, 256, 0, stream>>>(heO, Wsrc_em, nullptr, Cb, NE_N, 0);
  alproj_k<<<gWave, 256, 0, stream>>>(heO, Vs, als, NE_N);
  alproj_k<<<gWave, 256, 0, stream>>>(B, Vd, ald, NM_N);
  gat_agg_k<<<gWave, 256, 0, stream>>>(Cb, als, ald, offs_em, ssrc_em, b_em, hmO, NM_N);

  // ---- layer 1, conv me (src=mat B, dst=exp heO) -> heO = elu(oe) ----
  vfold_k<<<1, 512, 0, stream>>>(Wsrc_me, asrc_me, Vs);
  vfold_k<<<1, 512, 0, stream>>>(Wdst_me, adst_me, Vd);
  gemm128_k<<<gRow, 256, 0, stream>>>(B, Wsrc_me, nullptr, Cb, NM_N, 0);
  alproj_k<<<gWave, 256, 0, stream>>>(B, Vs, als, NM_N);
  alproj_k<<<gWave, 256, 0, stream>>>(heO, Vd, ald, NE_N);
  gat_agg_k<<<gWave, 256, 0, stream>>>(Cb, als, ald, offs_me, ssrc_me, b_me, heO, NE_N);

  // ---- layer 2: all GEMMs + logits BEFORE the (in-place) aggregations ----
  const float* Wsrc_em1 = Wsrc_em + 16384;
  const float* Wdst_em1 = Wdst_em + 16384;
  const float* asrc_em1 = asrc_em + 128;
  const float* adst_em1 = adst_em + 128;
  const float* Wsrc_me1 = Wsrc_me + 16384;
  const float* Wdst_me1 = Wdst_me + 16384;
  const float* asrc_me1 = asrc_me + 128;
  const float* adst_me1 = adst_me + 128;

  vfold_k<<<1, 512, 0, stream>>>(Wsrc_em1, asrc_em1, Vs);
  vfold_k<<<1, 512, 0, stream>>>(Wdst_em1, adst_em1, Vd);
  vfold_k<<<1, 512, 0, stream>>>(Wsrc_me1, asrc_me1, Vs2);
  vfold_k<<<1, 512, 0, stream>>>(Wdst_me1, adst_me1, Vd2);
  gemm128_k<<<gRow, 256, 0, stream>>>(heO, Wsrc_em1, nullptr, Cb, NE_N, 0);  // hs_em2
  alproj_k<<<gWave, 256, 0, stream>>>(heO, Vs, als, NE_N);
  alproj_k<<<gWave, 256, 0, stream>>>(hmO, Vd, ald, NM_N);
  gemm128_k<<<gRow, 256, 0, stream>>>(hmO, Wsrc_me1, nullptr, B, NM_N, 0);   // hs_me2
  alproj_k<<<gWave, 256, 0, stream>>>(hmO, Vs2, als2, NM_N);
  alproj_k<<<gWave, 256, 0, stream>>>(heO, Vd2, ald2, NE_N);
  gat_agg_k<<<gWave, 256, 0, stream>>>(Cb, als, ald, offs_em, ssrc_em, b_em + 128, hmO, NM_N);
  gat_agg_k<<<gWave, 256, 0, stream>>>(B, als2, ald2, offs_me, ssrc_me, b_me + 128, heO, NE_N);

  // ---- regressor on experiment nodes ----
  gemm128_k<<<gRow, 256, 0, stream>>>(heO, Wr1, br1, Cb, NE_N, 1);  // relu
  reg_tail_k<<<gWave, 256, 0, stream>>>(Cb, Wr2, br2, Wr3, br3, pred, NE_N);
}

// Round 2
// 908.144 us; speedup vs baseline: 1.2192x; 1.2192x over previous
//
#include <hip/hip_runtime.h>
#include <hip/hip_bf16.h>
#include <math.h>

#define NE_N 50000
#define NM_N 50000
#define NEDGE 500000

// -- GEMM: C[M,128] = A[M,128] @ W[128,128] (+bias)(+relu)
//    optional fused epilogue: als[r,h] = sum_d C_pre_bias[r, h*32+d] * aV[h*32+d]
__global__ __launch_bounds__(256) void gemm128_k(const float* __restrict__ A,
                                                 const float* __restrict__ W,
                                                 const float* __restrict__ bias,
                                                 float* __restrict__ C,
                                                 int M, int act,
                                                 const float* __restrict__ aV,
                                                 float* __restrict__ alsOut) {
  __shared__ float X[64][132];
  const int tid = threadIdx.x;
  const int row0 = blockIdx.x * 64;
#pragma unroll
  for (int i = 0; i < 8; ++i) {
    int q = tid + i * 256;
    int r = q >> 5;
    int k4 = (q & 31) << 2;
    float4 v = make_float4(0.f, 0.f, 0.f, 0.f);
    if (row0 + r < M) v = *(const float4*)&A[(size_t)(row0 + r) * 128 + k4];
    *(float4*)&X[r][k4] = v;
  }
  __syncthreads();
  const int cg = tid & 15, rq = tid >> 4;
  const int c0 = cg * 8;
  float acc[4][8];
#pragma unroll
  for (int s = 0; s < 4; ++s)
#pragma unroll
    for (int j = 0; j < 8; ++j) acc[s][j] = 0.f;

#pragma unroll 4
  for (int k = 0; k < 128; ++k) {
    float xv[4] = {X[rq][k], X[rq + 16][k], X[rq + 32][k], X[rq + 48][k]};
    float4 w0 = *(const float4*)&W[k * 128 + c0];
    float4 w1 = *(const float4*)&W[k * 128 + c0 + 4];
    float wv[8] = {w0.x, w0.y, w0.z, w0.w, w1.x, w1.y, w1.z, w1.w};
#pragma unroll
    for (int s = 0; s < 4; ++s)
#pragma unroll
      for (int j = 0; j < 8; ++j) acc[s][j] = fmaf(xv[s], wv[j], acc[s][j]);
  }

  if (aV) {  // fused src-logit epilogue (bias is nullptr for these calls)
    const float* av = &aV[c0];
    int h = cg >> 2;
    float p[4];
#pragma unroll
    for (int s = 0; s < 4; ++s) {
      float t = 0.f;
#pragma unroll
      for (int j = 0; j < 8; ++j) t = fmaf(acc[s][j], av[j], t);
      t += __shfl_xor(t, 1, 64);
      t += __shfl_xor(t, 2, 64);
      p[s] = t;
    }
    if ((cg & 3) == 0) {
#pragma unroll
      for (int s = 0; s < 4; ++s) {
        int r = row0 + rq + 16 * s;
        if (r < M) alsOut[(size_t)r * 4 + h] = p[s];
      }
    }
  }

#pragma unroll
  for (int s = 0; s < 4; ++s) {
    int r = row0 + rq + 16 * s;
    if (r >= M) continue;
    float o[8];
#pragma unroll
    for (int j = 0; j < 8; ++j) {
      float v = acc[s][j] + (bias ? bias[c0 + j] : 0.f);
      if (act == 1) v = fmaxf(v, 0.f);
      o[j] = v;
    }
    *(float4*)&C[(size_t)r * 128 + c0] = make_float4(o[0], o[1], o[2], o[3]);
    *(float4*)&C[(size_t)r * 128 + c0 + 4] = make_float4(o[4], o[5], o[6], o[7]);
  }
}

// -- V[k,h] = sum_d W[k, h*32+d] * a[h*32+d] (fold dst attention vector)
__global__ void vfold_k(const float* __restrict__ W, const float* __restrict__ a,
                        float* __restrict__ V) {
  int t = threadIdx.x;  // 512 threads
  int k = t >> 2, h = t & 3;
  float s = 0.f;
#pragma unroll
  for (int d = 0; d < 32; ++d) s += W[k * 128 + h * 32 + d] * a[h * 32 + d];
  V[k * 4 + h] = s;
}

// -- al[n,h] = sum_k X[n,k] * V[k,h] (one wave per node) — dst-side logits
__global__ __launch_bounds__(256) void alproj_k(const float* __restrict__ X,
                                                const float* __restrict__ V,
                                                float* __restrict__ al, int N) {
  int lane = threadIdx.x & 63;
  int n = (blockIdx.x * 256 + threadIdx.x) >> 6;
  if (n >= N) return;
  float x0 = X[(size_t)n * 128 + lane];
  float x1 = X[(size_t)n * 128 + 64 + lane];
  float p[4];
#pragma unroll
  for (int h = 0; h < 4; ++h)
    p[h] = x0 * V[lane * 4 + h] + x1 * V[(64 + lane) * 4 + h];
  for (int off = 32; off > 0; off >>= 1) {
#pragma unroll
    for (int h = 0; h < 4; ++h) p[h] += __shfl_xor(p[h], off, 64);
  }
  if (lane == 0) {
#pragma unroll
    for (int h = 0; h < 4; ++h) al[(size_t)n * 4 + h] = p[h];
  }
}

// -- counting sort of edges by dst ------------------------------------------
__global__ void hist_k(const int* __restrict__ dst, int* __restrict__ cnt, int E) {
  int e = blockIdx.x * blockDim.x + threadIdx.x;
  if (e < E) atomicAdd(&cnt[dst[e]], 1);
}

// 3-phase exclusive scan: A) per-4096-chunk, B) chunk sums, C) add back
__global__ __launch_bounds__(256) void scanA_k(const int* __restrict__ cnt,
                                               int* __restrict__ offs,
                                               int* __restrict__ sums, int n) {
  __shared__ int ts[256];
  int tid = threadIdx.x;
  int base = blockIdx.x * 4096 + tid * 16;
  int v[16];
  int s = 0;
#pragma unroll
  for (int i = 0; i < 16; ++i) {
    v[i] = (base + i < n) ? cnt[base + i] : 0;
    s += v[i];
  }
  ts[tid] = s;
  __syncthreads();
  for (int off = 1; off < 256; off <<= 1) {
    int t = (tid >= off) ? ts[tid - off] : 0;
    __syncthreads();
    ts[tid] += t;
    __syncthreads();
  }
  int run = ts[tid] - s;  // exclusive prefix of this thread's 16
#pragma unroll
  for (int i = 0; i < 16; ++i) {
    if (base + i < n) offs[base + i] = run;
    run += v[i];
  }
  if (tid == 255) sums[blockIdx.x] = ts[255];
}

__global__ void scanB_k(int* __restrict__ sums, int nchunk) {
  if (threadIdx.x == 0) {
    int acc = 0;
    for (int i = 0; i < nchunk; ++i) {
      int t = sums[i];
      sums[i] = acc;
      acc += t;
    }
    sums[nchunk] = acc;
  }
}

__global__ void scanC_k(int* __restrict__ offs, const int* __restrict__ sums, int n) {
  int i = blockIdx.x * blockDim.x + threadIdx.x;
  if (i < n) offs[i] += sums[i >> 12];
  if (i == 0) offs[n] = sums[(n + 4095) >> 12];
}

__global__ void scatter_k(const int* __restrict__ src, const int* __restrict__ dst,
                          const int* __restrict__ offs, int* __restrict__ cur,
                          int* __restrict__ ssrc, int E) {
  int e = blockIdx.x * blockDim.x + threadIdx.x;
  if (e < E) {
    int d = dst[e];
    int pos = offs[d] + atomicAdd(&cur[d], 1);
    ssrc[pos] = src[e];
  }
}

// -- per-dst softmax aggregation, two-pass (max, then sum), +bias +ELU ------
__global__ __launch_bounds__(256) void gat_agg_k(const float* __restrict__ hs,
    const float* __restrict__ als, const float* __restrict__ ald,
    const int* __restrict__ offs, const int* __restrict__ ssrc,
    const float* __restrict__ bias, float* __restrict__ out, int Ndst) {
  int lane = threadIdx.x & 63;
  int n = (blockIdx.x * 256 + threadIdx.x) >> 6;
  if (n >= Ndst) return;
  int h = lane >> 4;
  float ad = ald[(size_t)n * 4 + h];
  int i0 = offs[n], i1 = offs[n + 1];
  float m = -INFINITY;
  for (int i = i0; i < i1; ++i) {
    int s = ssrc[i];
    float e = als[(size_t)s * 4 + h] + ad;
    e = (e > 0.f) ? e : 0.2f * e;  // leaky_relu 0.2
    m = fmaxf(m, e);
  }
  float den = 0.f, a0 = 0.f, a1 = 0.f;
  for (int i = i0; i < i1; ++i) {
    int s = ssrc[i];
    float e = als[(size_t)s * 4 + h] + ad;
    e = (e > 0.f) ? e : 0.2f * e;
    float p = __expf(e - m);
    float2 hv = *(const float2*)&hs[(size_t)s * 128 + 2 * lane];
    a0 = fmaf(p, hv.x, a0);
    a1 = fmaf(p, hv.y, a1);
    den += p;
  }
  float inv = 1.f / (den + 1e-16f);
  float r0 = a0 * inv + bias[2 * lane];
  float r1 = a1 * inv + bias[2 * lane + 1];
  r0 = (r0 > 0.f) ? r0 : expm1f(r0);  // ELU
  r1 = (r1 > 0.f) ? r1 : expm1f(r1);
  *(float2*)&out[(size_t)n * 128 + 2 * lane] = make_float2(r0, r1);
}

// -- fused regressor tail: pred = relu(h1@W2+b2) @ W3 + b3  (GEMM-style) ----
__global__ __launch_bounds__(256) void regfuse_k(const float* __restrict__ h1,
    const float* __restrict__ W2, const float* __restrict__ b2,
    const float* __restrict__ W3, const float* __restrict__ b3,
    float* __restrict__ pred, int M) {
  __shared__ float X[64][132];
  const int tid = threadIdx.x;
  const int row0 = blockIdx.x * 64;
#pragma unroll
  for (int i = 0; i < 8; ++i) {
    int q = tid + i * 256;
    int r = q >> 5;
    int k4 = (q & 31) << 2;
    float4 v = make_float4(0.f, 0.f, 0.f, 0.f);
    if (row0 + r < M) v = *(const float4*)&h1[(size_t)(row0 + r) * 128 + k4];
    *(float4*)&X[r][k4] = v;
  }
  __syncthreads();
  const int cg = tid & 15, rq = tid >> 4;
  const int c0 = cg * 4;
  float acc[4][4];
#pragma unroll
  for (int s = 0; s < 4; ++s)
#pragma unroll
    for (int j = 0; j < 4; ++j) acc[s][j] = 0.f;
#pragma unroll 4
  for (int k = 0; k < 128; ++k) {
    float xv[4] = {X[rq][k], X[rq + 16][k], X[rq + 32][k], X[rq + 48][k]};
    float4 w = *(const float4*)&W2[k * 64 + c0];
#pragma unroll
    for (int s = 0; s < 4; ++s) {
      acc[s][0] = fmaf(xv[s], w.x, acc[s][0]);
      acc[s][1] = fmaf(xv[s], w.y, acc[s][1]);
      acc[s][2] = fmaf(xv[s], w.z, acc[s][2]);
      acc[s][3] = fmaf(xv[s], w.w, acc[s][3]);
    }
  }
  float4 b = *(const float4*)&b2[c0];
  float4 w3 = *(const float4*)&W3[c0];
  float bb[4] = {b.x, b.y, b.z, b.w};
  float ww[4] = {w3.x, w3.y, w3.z, w3.w};
#pragma unroll
  for (int s = 0; s < 4; ++s) {
    float v = 0.f;
#pragma unroll
    for (int j = 0; j < 4; ++j) v = fmaf(fmaxf(acc[s][j] + bb[j], 0.f), ww[j], v);
    v += __shfl_xor(v, 1, 64);
    v += __shfl_xor(v, 2, 64);
    v += __shfl_xor(v, 4, 64);
    v += __shfl_xor(v, 8, 64);
    int r = row0 + rq + 16 * s;
    if (cg == 0 && r < M) pred[r] = v + b3[0];
  }
}

extern "C" void kernel_launch(void* const* d_in, const int* in_sizes, int n_in,
                              void* d_out, int out_size, void* d_ws, size_t ws_size,
                              hipStream_t stream) {
  const float* x_exp   = (const float*)d_in[0];
  const float* x_mat   = (const float*)d_in[1];
  const int*   ei_em   = (const int*)d_in[2];
  const int*   ei_me   = (const int*)d_in[3];
  const float* Win_exp = (const float*)d_in[4];
  const float* bin_exp = (const float*)d_in[5];
  const float* Win_mat = (const float*)d_in[6];
  const float* bin_mat = (const float*)d_in[7];
  const float* Wsrc_em = (const float*)d_in[8];
  const float* Wdst_em = (const float*)d_in[9];
  const float* asrc_em = (const float*)d_in[10];
  const float* adst_em = (const float*)d_in[11];
  const float* b_em    = (const float*)d_in[12];
  const float* Wsrc_me = (const float*)d_in[13];
  const float* Wdst_me = (const float*)d_in[14];
  const float* asrc_me = (const float*)d_in[15];
  const float* adst_me = (const float*)d_in[16];
  const float* b_me    = (const float*)d_in[17];
  const float* Wr1     = (const float*)d_in[18];
  const float* br1     = (const float*)d_in[19];
  const float* Wr2     = (const float*)d_in[20];
  const float* br2     = (const float*)d_in[21];
  const float* Wr3     = (const float*)d_in[22];
  const float* br3     = (const float*)d_in[23];

  float* pred = (float*)d_out;
  float* heO  = pred + NE_N;
  float* hmO  = heO + (size_t)NE_N * 128;

  float* ws   = (float*)d_ws;
  float* B    = ws;
  float* Cb   = B + (size_t)NM_N * 128;
  float* als  = Cb + (size_t)NE_N * 128;
  float* ald  = als + 200000;
  float* als2 = ald + 200000;
  float* ald2 = als2 + 200000;
  int*   sums = (int*)(ald2 + 200000);           // scan chunk sums (<=64)
  float* Vd   = (float*)(sums + 64) + 448;       // keep old offsets roughly
  float* Vd2  = Vd + 512;
  int* offs_em = (int*)(Vd2 + 1024);
  int* cur_em  = offs_em + (NM_N + 1);
  int* ssrc_em = cur_em + NM_N;
  int* offs_me = ssrc_em + NEDGE;
  int* cur_me  = offs_me + (NE_N + 1);
  int* ssrc_me = cur_me + NE_N;

  const int* se = ei_em;
  const int* de = ei_em + NEDGE;
  const int* sm = ei_me;
  const int* dm = ei_me + NEDGE;

  const int gE = (NEDGE + 255) / 256;
  const int gRow = (NE_N + 63) / 64;
  const int gWave = (NE_N + 3) / 4;
  const int nChunkM = (NM_N + 4095) / 4096;
  const int nChunkE = (NE_N + 4095) / 4096;

  // ---- counting sort of both edge types by dst ----
  hipMemsetAsync(cur_em, 0, NM_N * sizeof(int), stream);
  hist_k<<<gE, 256, 0, stream>>>(de, cur_em, NEDGE);
  scanA_k<<<nChunkM, 256, 0, stream>>>(cur_em, offs_em, sums, NM_N);
  scanB_k<<<1, 64, 0, stream>>>(sums, nChunkM);
  scanC_k<<<(NM_N + 255) / 256, 256, 0, stream>>>(offs_em, sums, NM_N);
  hipMemsetAsync(cur_em, 0, NM_N * sizeof(int), stream);
  scatter_k<<<gE, 256, 0, stream>>>(se, de, offs_em, cur_em, ssrc_em, NEDGE);

  hipMemsetAsync(cur_me, 0, NE_N * sizeof(int), stream);
  hist_k<<<gE, 256, 0, stream>>>(dm, cur_me, NEDGE);
  scanA_k<<<nChunkE, 256, 0, stream>>>(cur_me, offs_me, sums, NE_N);
  scanB_k<<<1, 64, 0, stream>>>(sums, nChunkE);
  scanC_k<<<(NE_N + 255) / 256, 256, 0, stream>>>(offs_me, sums, NE_N);
  hipMemsetAsync(cur_me, 0, NE_N * sizeof(int), stream);
  scatter_k<<<gE, 256, 0, stream>>>(sm, dm, offs_me, cur_me, ssrc_me, NEDGE);

  // ---- input projections ----
  gemm128_k<<<gRow, 256, 0, stream>>>(x_exp, Win_exp, bin_exp, heO, NE_N, 0, nullptr, nullptr);
  gemm128_k<<<gRow, 256, 0, stream>>>(x_mat, Win_mat, bin_mat, B, NM_N, 0, nullptr, nullptr);

  // ---- layer 1, conv em (src=exp heO, dst=mat B) -> hmO ----
  vfold_k<<<1, 512, 0, stream>>>(Wdst_em, adst_em, Vd);
  gemm128_k<<<gRow, 256, 0, stream>>>(heO, Wsrc_em, nullptr, Cb, NE_N, 0, asrc_em, als);
  alproj_k<<<gWave, 256, 0, stream>>>(B, Vd, ald, NM_N);
  gat_agg_k<<<gWave, 256, 0, stream>>>(Cb, als, ald, offs_em, ssrc_em, b_em, hmO, NM_N);

  // ---- layer 1, conv me (src=mat B, dst=exp heO) -> heO ----
  vfold_k<<<1, 512, 0, stream>>>(Wdst_me, adst_me, Vd);
  gemm128_k<<<gRow, 256, 0, stream>>>(B, Wsrc_me, nullptr, Cb, NM_N, 0, asrc_me, als);
  alproj_k<<<gWave, 256, 0, stream>>>(heO, Vd, ald, NE_N);
  gat_agg_k<<<gWave, 256, 0, stream>>>(Cb, als, ald, offs_me, ssrc_me, b_me, heO, NE_N);

  // ---- layer 2 ----
  const float* Wsrc_em1 = Wsrc_em + 16384;
  const float* Wdst_em1 = Wdst_em + 16384;
  const float* asrc_em1 = asrc_em + 128;
  const float* adst_em1 = adst_em + 128;
  const float* Wsrc_me1 = Wsrc_me + 16384;
  const float* Wdst_me1 = Wdst_me + 16384;
  const float* asrc_me1 = asrc_me + 128;
  const float* adst_me1 = adst_me + 128;

  vfold_k<<<1, 512, 0, stream>>>(Wdst_em1, adst_em1, Vd);
  vfold_k<<<1, 512, 0, stream>>>(Wdst_me1, adst_me1, Vd2);
  gemm128_k<<<gRow, 256, 0, stream>>>(heO, Wsrc_em1, nullptr, Cb, NE_N, 0, asrc_em1, als);
  alproj_k<<<gWave, 256, 0, stream>>>(hmO, Vd, ald, NM_N);
  gemm128_k<<<gRow, 256, 0, stream>>>(hmO, Wsrc_me1, nullptr, B, NM_N, 0, asrc_me1, als2);
  alproj_k<<<gWave, 256, 0, stream>>>(heO, Vd2, ald2, NE_N);
  gat_agg_k<<<gWave, 256, 0, stream>>>(Cb, als, ald, offs_em, ssrc_em, b_em + 128, hmO, NM_N);
  gat_agg_k<<<gWave, 256, 0, stream>>>(B, als2, ald2, offs_me, ssrc_me, b_me + 128, heO, NE_N);

  // ---- regressor ----
  gemm128_k<<<gRow, 256, 0, stream>>>(heO, Wr1, br1, Cb, NE_N, 1, nullptr, nullptr);
  regfuse_k<<<gRow, 256, 0, stream>>>(Cb, Wr2, br2, Wr3, br3, pred, NE_N);
}

// Round 3
// 678.760 us; speedup vs baseline: 1.6313x; 1.3379x over previous
//
#include <hip/hip_runtime.h>
#include <hip/hip_bf16.h>
#include <math.h>

#define NE_N 50000
#define NM_N 50000
#define NEDGE 500000

// -- GEMM: C[M,128] = A[M,128] @ W[128,128] (+bias)(+relu)
//    optional epilogue 1 (aV/alsOut): src logits als[r,h] = sum_{d in head h} C_pre_bias * aV
//    optional epilogue 2 (Vald/aldOut): dst logits ald[r,h] = sum_k (C post-bias)[r,k] * Vald[k,h]
__global__ __launch_bounds__(256) void gemm128_k(const float* __restrict__ A,
                                                 const float* __restrict__ W,
                                                 const float* __restrict__ bias,
                                                 float* __restrict__ C,
                                                 int M, int act,
                                                 const float* __restrict__ aV,
                                                 float* __restrict__ alsOut,
                                                 const float* __restrict__ Vald,
                                                 float* __restrict__ aldOut) {
  __shared__ float X[64][132];
  const int tid = threadIdx.x;
  const int row0 = blockIdx.x * 64;
#pragma unroll
  for (int i = 0; i < 8; ++i) {
    int q = tid + i * 256;
    int r = q >> 5;
    int k4 = (q & 31) << 2;
    float4 v = make_float4(0.f, 0.f, 0.f, 0.f);
    if (row0 + r < M) v = *(const float4*)&A[(size_t)(row0 + r) * 128 + k4];
    *(float4*)&X[r][k4] = v;
  }
  __syncthreads();
  const int cg = tid & 15, rq = tid >> 4;
  const int c0 = cg * 8;
  float acc[4][8];
#pragma unroll
  for (int s = 0; s < 4; ++s)
#pragma unroll
    for (int j = 0; j < 8; ++j) acc[s][j] = 0.f;

#pragma unroll 4
  for (int k = 0; k < 128; ++k) {
    float xv[4] = {X[rq][k], X[rq + 16][k], X[rq + 32][k], X[rq + 48][k]};
    float4 w0 = *(const float4*)&W[k * 128 + c0];
    float4 w1 = *(const float4*)&W[k * 128 + c0 + 4];
    float wv[8] = {w0.x, w0.y, w0.z, w0.w, w1.x, w1.y, w1.z, w1.w};
#pragma unroll
    for (int s = 0; s < 4; ++s)
#pragma unroll
      for (int j = 0; j < 8; ++j) acc[s][j] = fmaf(xv[s], wv[j], acc[s][j]);
  }

  if (aV) {  // src-logit epilogue on pre-bias acc (hs GEMMs have no bias)
    const float* av = &aV[c0];
    int h = cg >> 2;
    float p[4];
#pragma unroll
    for (int s = 0; s < 4; ++s) {
      float t = 0.f;
#pragma unroll
      for (int j = 0; j < 8; ++j) t = fmaf(acc[s][j], av[j], t);
      t += __shfl_xor(t, 1, 64);
      t += __shfl_xor(t, 2, 64);
      p[s] = t;
    }
    if ((cg & 3) == 0) {
#pragma unroll
      for (int s = 0; s < 4; ++s) {
        int r = row0 + rq + 16 * s;
        if (r < M) alsOut[(size_t)r * 4 + h] = p[s];
      }
    }
  }

  float vv[8][4];
  if (Vald) {
#pragma unroll
    for (int j = 0; j < 8; ++j) {
      float4 t = *(const float4*)&Vald[(c0 + j) * 4];
      vv[j][0] = t.x; vv[j][1] = t.y; vv[j][2] = t.z; vv[j][3] = t.w;
    }
  }
  float part[4][4];
#pragma unroll
  for (int s = 0; s < 4; ++s)
#pragma unroll
    for (int h = 0; h < 4; ++h) part[s][h] = 0.f;

#pragma unroll
  for (int s = 0; s < 4; ++s) {
    int r = row0 + rq + 16 * s;
    float o[8];
#pragma unroll
    for (int j = 0; j < 8; ++j) {
      float v = acc[s][j] + (bias ? bias[c0 + j] : 0.f);
      if (act == 1) v = fmaxf(v, 0.f);
      o[j] = v;
    }
    if (r < M) {
      *(float4*)&C[(size_t)r * 128 + c0] = make_float4(o[0], o[1], o[2], o[3]);
      *(float4*)&C[(size_t)r * 128 + c0 + 4] = make_float4(o[4], o[5], o[6], o[7]);
    }
    if (Vald) {
#pragma unroll
      for (int j = 0; j < 8; ++j) {
#pragma unroll
        for (int h = 0; h < 4; ++h) part[s][h] = fmaf(o[j], vv[j][h], part[s][h]);
      }
    }
  }
  if (Vald) {
#pragma unroll
    for (int s = 0; s < 4; ++s) {
#pragma unroll
      for (int off = 1; off < 16; off <<= 1) {
#pragma unroll
        for (int h = 0; h < 4; ++h) part[s][h] += __shfl_xor(part[s][h], off, 64);
      }
    }
    if (cg == 0) {
#pragma unroll
      for (int s = 0; s < 4; ++s) {
        int r = row0 + rq + 16 * s;
        if (r < M)
          *(float4*)&aldOut[(size_t)r * 4] =
              make_float4(part[s][0], part[s][1], part[s][2], part[s][3]);
      }
    }
  }
}

// -- batched fold: V[idx][k,h] = sum_d Wdst[k, h*32+d] * adst[h*32+d]
//    idx = blockIdx.x: 0=em layer0, 1=me layer0, 2=em layer1, 3=me layer1
__global__ void vfold4_k(const float* __restrict__ Wem, const float* __restrict__ aem,
                         const float* __restrict__ Wme, const float* __restrict__ ame,
                         float* __restrict__ Vbase) {
  int idx = blockIdx.x;
  int layer = idx >> 1, et = idx & 1;
  const float* W = (et ? Wme : Wem) + layer * 16384;
  const float* a = (et ? ame : aem) + layer * 128;
  float* V = Vbase + idx * 512;
  int t = threadIdx.x;  // 512
  int k = t >> 2, h = t & 3;
  float s = 0.f;
#pragma unroll
  for (int d = 0; d < 32; ++d) s += W[k * 128 + h * 32 + d] * a[h * 32 + d];
  V[k * 4 + h] = s;
}

// -- counting sort of edges by dst ------------------------------------------
__global__ void hist_k(const int* __restrict__ dst, int* __restrict__ cnt, int E) {
  int e = blockIdx.x * blockDim.x + threadIdx.x;
  if (e < E) atomicAdd(&cnt[dst[e]], 1);
}

__global__ __launch_bounds__(256) void scanA_k(const int* __restrict__ cnt,
                                               int* __restrict__ offs,
                                               int* __restrict__ sums, int n) {
  __shared__ int ts[256];
  int tid = threadIdx.x;
  int base = blockIdx.x * 4096 + tid * 16;
  int v[16];
  int s = 0;
#pragma unroll
  for (int i = 0; i < 16; ++i) {
    v[i] = (base + i < n) ? cnt[base + i] : 0;
    s += v[i];
  }
  ts[tid] = s;
  __syncthreads();
  for (int off = 1; off < 256; off <<= 1) {
    int t = (tid >= off) ? ts[tid - off] : 0;
    __syncthreads();
    ts[tid] += t;
    __syncthreads();
  }
  int run = ts[tid] - s;
#pragma unroll
  for (int i = 0; i < 16; ++i) {
    if (base + i < n) offs[base + i] = run;
    run += v[i];
  }
  if (tid == 255) sums[blockIdx.x] = ts[255];
}

__global__ void scanB_k(int* __restrict__ sums, int nchunk) {
  if (threadIdx.x == 0) {
    int acc = 0;
    for (int i = 0; i < nchunk; ++i) {
      int t = sums[i];
      sums[i] = acc;
      acc += t;
    }
    sums[nchunk] = acc;
  }
}

__global__ void scanC_k(int* __restrict__ offs, const int* __restrict__ sums, int n) {
  int i = blockIdx.x * blockDim.x + threadIdx.x;
  if (i < n) offs[i] += sums[i >> 12];
  if (i == 0) offs[n] = sums[(n + 4095) >> 12];
}

__global__ void scatter_k(const int* __restrict__ src, const int* __restrict__ dst,
                          const int* __restrict__ offs, int* __restrict__ cur,
                          int* __restrict__ ssrc, int E) {
  int e = blockIdx.x * blockDim.x + threadIdx.x;
  if (e < E) {
    int d = dst[e];
    int pos = offs[d] + atomicAdd(&cur[d], 1);
    ssrc[pos] = src[e];
  }
}

// -- per-dst softmax aggregation, lane-parallel logits + batched gathers ----
//    optional epilogue: aldOut[n,h] = sum_k out[n,k] * Vald[k,h] (post-ELU)
__global__ __launch_bounds__(256) void gat_agg_k(const float* __restrict__ hs,
    const float* __restrict__ als, const float* ald,
    const int* __restrict__ offs, const int* __restrict__ ssrc,
    const float* __restrict__ bias, float* __restrict__ out, int Ndst,
    const float* __restrict__ Vald, float* aldOut) {
  const int lane = threadIdx.x & 63;
  const int n = (blockIdx.x * 256 + threadIdx.x) >> 6;
  if (n >= Ndst) return;
  const int h = lane >> 4;
  const int j = lane & 15;
  const int b = lane & 48;  // h<<4
  const float ad = ald[(size_t)n * 4 + h];
  const int i0 = offs[n], i1 = offs[n + 1];
  const int deg = i1 - i0;
  float m_run = -INFINITY, den = 0.f, acc0 = 0.f, acc1 = 0.f;
  for (int chunk = 0; chunk < deg; chunk += 16) {
    const int cnt = min(16, deg - chunk);
    const int idx = i0 + chunk + ((j < cnt) ? j : (cnt - 1));
    const int sv = ssrc[idx];
    float e = als[(size_t)sv * 4 + h] + ad;
    e = (e > 0.f) ? e : 0.2f * e;  // leaky_relu 0.2
    if (j >= cnt) e = -INFINITY;
    float mc = e;
    mc = fmaxf(mc, __shfl_xor(mc, 1, 64));
    mc = fmaxf(mc, __shfl_xor(mc, 2, 64));
    mc = fmaxf(mc, __shfl_xor(mc, 4, 64));
    mc = fmaxf(mc, __shfl_xor(mc, 8, 64));
    const float mn = fmaxf(m_run, mc);
    const float p = __expf(e - mn);      // 0 for masked lanes (e=-inf)
    const float sc = __expf(m_run - mn); // 0 on first chunk
    float dc = p;
    dc += __shfl_xor(dc, 1, 64);
    dc += __shfl_xor(dc, 2, 64);
    dc += __shfl_xor(dc, 4, 64);
    dc += __shfl_xor(dc, 8, 64);
    den = den * sc + dc;
    acc0 *= sc;
    acc1 *= sc;
    m_run = mn;
    int jj = 0;
    for (; jj + 4 <= cnt; jj += 4) {
      int s0 = __shfl(sv, b + jj, 64);
      int s1 = __shfl(sv, b + jj + 1, 64);
      int s2 = __shfl(sv, b + jj + 2, 64);
      int s3 = __shfl(sv, b + jj + 3, 64);
      float q0 = __shfl(p, b + jj, 64);
      float q1 = __shfl(p, b + jj + 1, 64);
      float q2 = __shfl(p, b + jj + 2, 64);
      float q3 = __shfl(p, b + jj + 3, 64);
      float2 v0 = *(const float2*)&hs[(size_t)s0 * 128 + 2 * lane];
      float2 v1 = *(const float2*)&hs[(size_t)s1 * 128 + 2 * lane];
      float2 v2 = *(const float2*)&hs[(size_t)s2 * 128 + 2 * lane];
      float2 v3 = *(const float2*)&hs[(size_t)s3 * 128 + 2 * lane];
      acc0 = fmaf(q0, v0.x, acc0); acc1 = fmaf(q0, v0.y, acc1);
      acc0 = fmaf(q1, v1.x, acc0); acc1 = fmaf(q1, v1.y, acc1);
      acc0 = fmaf(q2, v2.x, acc0); acc1 = fmaf(q2, v2.y, acc1);
      acc0 = fmaf(q3, v3.x, acc0); acc1 = fmaf(q3, v3.y, acc1);
    }
    for (; jj < cnt; ++jj) {
      int s0 = __shfl(sv, b + jj, 64);
      float q0 = __shfl(p, b + jj, 64);
      float2 v0 = *(const float2*)&hs[(size_t)s0 * 128 + 2 * lane];
      acc0 = fmaf(q0, v0.x, acc0);
      acc1 = fmaf(q0, v0.y, acc1);
    }
  }
  const float inv = 1.f / (den + 1e-16f);
  float r0 = acc0 * inv + bias[2 * lane];
  float r1 = acc1 * inv + bias[2 * lane + 1];
  r0 = (r0 > 0.f) ? r0 : expm1f(r0);  // ELU
  r1 = (r1 > 0.f) ? r1 : expm1f(r1);
  *(float2*)&out[(size_t)n * 128 + 2 * lane] = make_float2(r0, r1);
  if (Vald) {
    const float4 w0 = *(const float4*)&Vald[(2 * lane) * 4];
    const float4 w1 = *(const float4*)&Vald[(2 * lane + 1) * 4];
    float t0 = fmaf(r0, w0.x, r1 * w1.x);
    float t1 = fmaf(r0, w0.y, r1 * w1.y);
    float t2 = fmaf(r0, w0.z, r1 * w1.z);
    float t3 = fmaf(r0, w0.w, r1 * w1.w);
#pragma unroll
    for (int off = 1; off < 64; off <<= 1) {
      t0 += __shfl_xor(t0, off, 64);
      t1 += __shfl_xor(t1, off, 64);
      t2 += __shfl_xor(t2, off, 64);
      t3 += __shfl_xor(t3, off, 64);
    }
    if (lane == 0)
      *(float4*)&aldOut[(size_t)n * 4] = make_float4(t0, t1, t2, t3);
  }
}

// -- fused regressor tail: pred = relu(h1@W2+b2) @ W3 + b3 ------------------
__global__ __launch_bounds__(256) void regfuse_k(const float* __restrict__ h1,
    const float* __restrict__ W2, const float* __restrict__ b2,
    const float* __restrict__ W3, const float* __restrict__ b3,
    float* __restrict__ pred, int M) {
  __shared__ float X[64][132];
  const int tid = threadIdx.x;
  const int row0 = blockIdx.x * 64;
#pragma unroll
  for (int i = 0; i < 8; ++i) {
    int q = tid + i * 256;
    int r = q >> 5;
    int k4 = (q & 31) << 2;
    float4 v = make_float4(0.f, 0.f, 0.f, 0.f);
    if (row0 + r < M) v = *(const float4*)&h1[(size_t)(row0 + r) * 128 + k4];
    *(float4*)&X[r][k4] = v;
  }
  __syncthreads();
  const int cg = tid & 15, rq = tid >> 4;
  const int c0 = cg * 4;
  float acc[4][4];
#pragma unroll
  for (int s = 0; s < 4; ++s)
#pragma unroll
    for (int j = 0; j < 4; ++j) acc[s][j] = 0.f;
#pragma unroll 4
  for (int k = 0; k < 128; ++k) {
    float xv[4] = {X[rq][k], X[rq + 16][k], X[rq + 32][k], X[rq + 48][k]};
    float4 w = *(const float4*)&W2[k * 64 + c0];
#pragma unroll
    for (int s = 0; s < 4; ++s) {
      acc[s][0] = fmaf(xv[s], w.x, acc[s][0]);
      acc[s][1] = fmaf(xv[s], w.y, acc[s][1]);
      acc[s][2] = fmaf(xv[s], w.z, acc[s][2]);
      acc[s][3] = fmaf(xv[s], w.w, acc[s][3]);
    }
  }
  float4 bq = *(const float4*)&b2[c0];
  float4 w3 = *(const float4*)&W3[c0];
  float bb[4] = {bq.x, bq.y, bq.z, bq.w};
  float ww[4] = {w3.x, w3.y, w3.z, w3.w};
#pragma unroll
  for (int s = 0; s < 4; ++s) {
    float v = 0.f;
#pragma unroll
    for (int j = 0; j < 4; ++j) v = fmaf(fmaxf(acc[s][j] + bb[j], 0.f), ww[j], v);
    v += __shfl_xor(v, 1, 64);
    v += __shfl_xor(v, 2, 64);
    v += __shfl_xor(v, 4, 64);
    v += __shfl_xor(v, 8, 64);
    int r = row0 + rq + 16 * s;
    if (cg == 0 && r < M) pred[r] = v + b3[0];
  }
}

extern "C" void kernel_launch(void* const* d_in, const int* in_sizes, int n_in,
                              void* d_out, int out_size, void* d_ws, size_t ws_size,
                              hipStream_t stream) {
  const float* x_exp   = (const float*)d_in[0];
  const float* x_mat   = (const float*)d_in[1];
  const int*   ei_em   = (const int*)d_in[2];
  const int*   ei_me   = (const int*)d_in[3];
  const float* Win_exp = (const float*)d_in[4];
  const float* bin_exp = (const float*)d_in[5];
  const float* Win_mat = (const float*)d_in[6];
  const float* bin_mat = (const float*)d_in[7];
  const float* Wsrc_em = (const float*)d_in[8];
  const float* Wdst_em = (const float*)d_in[9];
  const float* asrc_em = (const float*)d_in[10];
  const float* adst_em = (const float*)d_in[11];
  const float* b_em    = (const float*)d_in[12];
  const float* Wsrc_me = (const float*)d_in[13];
  const float* Wdst_me = (const float*)d_in[14];
  const float* asrc_me = (const float*)d_in[15];
  const float* adst_me = (const float*)d_in[16];
  const float* b_me    = (const float*)d_in[17];
  const float* Wr1     = (const float*)d_in[18];
  const float* br1     = (const float*)d_in[19];
  const float* Wr2     = (const float*)d_in[20];
  const float* br2     = (const float*)d_in[21];
  const float* Wr3     = (const float*)d_in[22];
  const float* br3     = (const float*)d_in[23];

  float* pred = (float*)d_out;
  float* heO  = pred + NE_N;
  float* hmO  = heO + (size_t)NE_N * 128;

  float* ws   = (float*)d_ws;
  float* B    = ws;
  float* Cb   = B + (size_t)NM_N * 128;
  float* alsA = Cb + (size_t)NE_N * 128;
  float* alsB = alsA + 200000;
  float* aldE = alsB + 200000;
  float* aldM = aldE + 200000;
  int*   sums = (int*)(aldM + 200000);
  float* Vb   = (float*)(sums + 64);     // 4 * 512 folded dst vectors
  int* offs_em = (int*)(Vb + 2048);
  int* cur_em  = offs_em + (NM_N + 1);
  int* ssrc_em = cur_em + NM_N;
  int* offs_me = ssrc_em + NEDGE;
  int* cur_me  = offs_me + (NE_N + 1);
  int* ssrc_me = cur_me + NE_N;

  const int* se = ei_em;
  const int* de = ei_em + NEDGE;
  const int* sm = ei_me;
  const int* dm = ei_me + NEDGE;

  const int gE = (NEDGE + 255) / 256;
  const int gRow = (NE_N + 63) / 64;
  const int gWave = (NE_N + 3) / 4;
  const int nChunkM = (NM_N + 4095) / 4096;
  const int nChunkE = (NE_N + 4095) / 4096;

  // ---- counting sort of both edge types by dst ----
  hipMemsetAsync(cur_em, 0, NM_N * sizeof(int), stream);
  hist_k<<<gE, 256, 0, stream>>>(de, cur_em, NEDGE);
  scanA_k<<<nChunkM, 256, 0, stream>>>(cur_em, offs_em, sums, NM_N);
  scanB_k<<<1, 64, 0, stream>>>(sums, nChunkM);
  scanC_k<<<(NM_N + 255) / 256, 256, 0, stream>>>(offs_em, sums, NM_N);
  hipMemsetAsync(cur_em, 0, NM_N * sizeof(int), stream);
  scatter_k<<<gE, 256, 0, stream>>>(se, de, offs_em, cur_em, ssrc_em, NEDGE);

  hipMemsetAsync(cur_me, 0, NE_N * sizeof(int), stream);
  hist_k<<<gE, 256, 0, stream>>>(dm, cur_me, NEDGE);
  scanA_k<<<nChunkE, 256, 0, stream>>>(cur_me, offs_me, sums, NE_N);
  scanB_k<<<1, 64, 0, stream>>>(sums, nChunkE);
  scanC_k<<<(NE_N + 255) / 256, 256, 0, stream>>>(offs_me, sums, NE_N);
  hipMemsetAsync(cur_me, 0, NE_N * sizeof(int), stream);
  scatter_k<<<gE, 256, 0, stream>>>(sm, dm, offs_me, cur_me, ssrc_me, NEDGE);

  // ---- folded dst attention vectors (4: em0, me0, em1, me1) ----
  vfold4_k<<<4, 512, 0, stream>>>(Wdst_em, adst_em, Wdst_me, adst_me, Vb);

  // ---- input projections, fused dst-logit epilogues ----
  gemm128_k<<<gRow, 256, 0, stream>>>(x_exp, Win_exp, bin_exp, heO, NE_N, 0,
                                      nullptr, nullptr, Vb + 512, aldE);   // me0 dst logits
  gemm128_k<<<gRow, 256, 0, stream>>>(x_mat, Win_mat, bin_mat, B, NM_N, 0,
                                      nullptr, nullptr, Vb, aldM);         // em0 dst logits

  // ---- layer 1, conv em (src=exp, dst=mat) -> hmO; epi: em1 dst logits ----
  gemm128_k<<<gRow, 256, 0, stream>>>(heO, Wsrc_em, nullptr, Cb, NE_N, 0,
                                      asrc_em, alsA, nullptr, nullptr);
  gat_agg_k<<<gWave, 256, 0, stream>>>(Cb, alsA, aldM, offs_em, ssrc_em, b_em,
                                       hmO, NM_N, Vb + 1024, aldM);

  // ---- layer 1, conv me (src=mat, dst=exp) -> heO; epi: me1 dst logits ----
  gemm128_k<<<gRow, 256, 0, stream>>>(B, Wsrc_me, nullptr, Cb, NM_N, 0,
                                      asrc_me, alsB, nullptr, nullptr);
  gat_agg_k<<<gWave, 256, 0, stream>>>(Cb, alsB, aldE, offs_me, ssrc_me, b_me,
                                       heO, NE_N, Vb + 1536, aldE);

  // ---- layer 2 ----
  gemm128_k<<<gRow, 256, 0, stream>>>(heO, Wsrc_em + 16384, nullptr, Cb, NE_N, 0,
                                      asrc_em + 128, alsA, nullptr, nullptr);
  gemm128_k<<<gRow, 256, 0, stream>>>(hmO, Wsrc_me + 16384, nullptr, B, NM_N, 0,
                                      asrc_me + 128, alsB, nullptr, nullptr);
  gat_agg_k<<<gWave, 256, 0, stream>>>(Cb, alsA, aldM, offs_em, ssrc_em,
                                       b_em + 128, hmO, NM_N, nullptr, nullptr);
  gat_agg_k<<<gWave, 256, 0, stream>>>(B, alsB, aldE, offs_me, ssrc_me,
                                       b_me + 128, heO, NE_N, nullptr, nullptr);

  // ---- regressor ----
  gemm128_k<<<gRow, 256, 0, stream>>>(heO, Wr1, br1, Cb, NE_N, 1,
                                      nullptr, nullptr, nullptr, nullptr);
  regfuse_k<<<gRow, 256, 0, stream>>>(Cb, Wr2, br2, Wr3, br3, pred, NE_N);
}

// Round 4
// 462.713 us; speedup vs baseline: 2.3929x; 1.4669x over previous
//
#include <hip/hip_runtime.h>
#include <hip/hip_bf16.h>
#include <math.h>

#define NE_N 50000
#define NM_N 50000
#define NEDGE 500000

typedef __attribute__((ext_vector_type(8))) short bf16x8;
typedef __attribute__((ext_vector_type(4))) float f32x4;

__device__ __forceinline__ ushort f2bf(float f) {
  uint u = __float_as_uint(f);
  u += 0x7fffu + ((u >> 16) & 1u);   // RNE
  return (ushort)(u >> 16);
}
__device__ __forceinline__ float bfl(uint u) { return __uint_as_float(u << 16); }
__device__ __forceinline__ float bfh(uint u) { return __uint_as_float(u & 0xffff0000u); }

// ---- cast fp32 -> bf16, 8 elems/thread -----------------------------------
__global__ __launch_bounds__(256) void cast_k(const float* __restrict__ x,
                                              ushort* __restrict__ o, int n8) {
  int i = blockIdx.x * 256 + threadIdx.x;
  if (i >= n8) return;
  float4 a = *(const float4*)&x[(size_t)i * 8];
  float4 b = *(const float4*)&x[(size_t)i * 8 + 4];
  ushort r[8] = {f2bf(a.x), f2bf(a.y), f2bf(a.z), f2bf(a.w),
                 f2bf(b.x), f2bf(b.y), f2bf(b.z), f2bf(b.w)};
  *(uint4*)&o[(size_t)i * 8] = *(uint4*)r;
}

// ---- cast + transpose 7 GEMM weights: Wt[n][k] = bf16(W[k][n]) -----------
__global__ __launch_bounds__(256) void wcast_k(const float* W0, const float* W1,
    const float* W2, const float* W3, const float* W4, const float* W5,
    const float* W6, ushort* __restrict__ Wt) {
  __shared__ float T[128][129];
  const float* W;
  switch (blockIdx.x) {
    case 0: W = W0; break; case 1: W = W1; break; case 2: W = W2; break;
    case 3: W = W3; break; case 4: W = W4; break; case 5: W = W5; break;
    default: W = W6;
  }
  int tid = threadIdx.x;
  for (int i = tid; i < 16384; i += 256) T[i >> 7][i & 127] = W[i];
  __syncthreads();
  uint* o = (uint*)(Wt + (size_t)blockIdx.x * 16384);
  for (int i = tid; i < 8192; i += 256) {
    int n = i >> 6, k2 = (i & 63) << 1;
    o[i] = (uint)f2bf(T[k2][n]) | ((uint)f2bf(T[k2 + 1][n]) << 16);
  }
}

// ---- MFMA bf16 GEMM: Cb[M,128](bf16) = A[M,128](bf16) @ Wt^T (+bias)(+relu)
//      fused: src logits (aV, pre-bias), dst logits (Vald, post-bias/act)
__global__ __launch_bounds__(256) void mgemm_k(const ushort* __restrict__ A,
    const ushort* __restrict__ Wt, const float* __restrict__ bias,
    ushort* __restrict__ Cb, int M, int act,
    const float* __restrict__ aV, float* __restrict__ alsOut,
    const float* __restrict__ Vald, float* __restrict__ aldOut) {
  __shared__ ushort sm[32768];  // 32KB A | 32KB W, both XOR-swizzled
  char* sA = (char*)sm;
  char* sW = (char*)(sm + 16384);
  const int tid = threadIdx.x;
  const int row0 = blockIdx.x * 128;
  // stage A tile (rows clamped for tail) and W, swizzle byte^=(row&7)<<4
#pragma unroll
  for (int i = 0; i < 8; ++i) {
    int l = (tid + i * 256) << 4;
    int rl = l >> 8;
    int rg = row0 + rl; rg = rg < M ? rg : M - 1;
    uint4 v = *(const uint4*)((const char*)A + (size_t)rg * 256 + (l & 255));
    *(uint4*)(sA + (l ^ ((rl & 7) << 4))) = v;
    uint4 w = *(const uint4*)((const char*)Wt + l);
    *(uint4*)(sW + (l ^ ((rl & 7) << 4))) = w;
  }
  __syncthreads();
  const int lane = tid & 63, wid = tid >> 6;
  const int l15 = lane & 15, lq = lane >> 4;
  const int wm = wid * 32;  // this wave's 32 rows
  f32x4 acc[2][8];
#pragma unroll
  for (int mt = 0; mt < 2; ++mt)
#pragma unroll
    for (int nt = 0; nt < 8; ++nt) {
      f32x4 z = {0.f, 0.f, 0.f, 0.f};
      acc[mt][nt] = z;
    }
#pragma unroll
  for (int ks = 0; ks < 4; ++ks) {
    int r0r = wm + l15;
    int o0 = (r0r << 8) + (ks << 6) + (lq << 4);
    bf16x8 af0 = *(const bf16x8*)(sA + (o0 ^ ((r0r & 7) << 4)));
    int r1r = r0r + 16;
    int o1 = (r1r << 8) + (ks << 6) + (lq << 4);
    bf16x8 af1 = *(const bf16x8*)(sA + (o1 ^ ((r1r & 7) << 4)));
#pragma unroll
    for (int nt = 0; nt < 8; ++nt) {
      int c = (nt << 4) + l15;
      int ob = (c << 8) + (ks << 6) + (lq << 4);
      bf16x8 bf = *(const bf16x8*)(sW + (ob ^ ((c & 7) << 4)));
      acc[0][nt] = __builtin_amdgcn_mfma_f32_16x16x32_bf16(af0, bf, acc[0][nt], 0, 0, 0);
      acc[1][nt] = __builtin_amdgcn_mfma_f32_16x16x32_bf16(af1, bf, acc[1][nt], 0, 0, 0);
    }
  }
  // per-lane column constants
  float aVv[8], bv[8];
  f32x4 vv[8];
#pragma unroll
  for (int nt = 0; nt < 8; ++nt) {
    int c = (nt << 4) + l15;
    aVv[nt] = aV ? aV[c] : 0.f;
    bv[nt] = bias ? bias[c] : 0.f;
    if (Vald) vv[nt] = *(const f32x4*)&Vald[c * 4];
  }
  // src logits (pre-bias): head h = nt>>1
  if (aV) {
#pragma unroll
    for (int mt = 0; mt < 2; ++mt)
#pragma unroll
      for (int rg = 0; rg < 4; ++rg) {
        float p0 = fmaf(acc[mt][0][rg], aVv[0], acc[mt][1][rg] * aVv[1]);
        float p1 = fmaf(acc[mt][2][rg], aVv[2], acc[mt][3][rg] * aVv[3]);
        float p2 = fmaf(acc[mt][4][rg], aVv[4], acc[mt][5][rg] * aVv[5]);
        float p3 = fmaf(acc[mt][6][rg], aVv[6], acc[mt][7][rg] * aVv[7]);
#pragma unroll
        for (int off = 1; off < 16; off <<= 1) {
          p0 += __shfl_xor(p0, off, 64);
          p1 += __shfl_xor(p1, off, 64);
          p2 += __shfl_xor(p2, off, 64);
          p3 += __shfl_xor(p3, off, 64);
        }
        int r = row0 + wm + mt * 16 + lq * 4 + rg;
        if (l15 == 0 && r < M)
          *(float4*)&alsOut[(size_t)r * 4] = make_float4(p0, p1, p2, p3);
      }
  }
  // bias + act
#pragma unroll
  for (int mt = 0; mt < 2; ++mt)
#pragma unroll
    for (int nt = 0; nt < 8; ++nt)
#pragma unroll
      for (int rg = 0; rg < 4; ++rg) {
        float v = acc[mt][nt][rg] + bv[nt];
        if (act) v = fmaxf(v, 0.f);
        acc[mt][nt][rg] = v;
      }
  // dst logits (post-bias/act)
  if (Vald) {
#pragma unroll
    for (int mt = 0; mt < 2; ++mt)
#pragma unroll
      for (int rg = 0; rg < 4; ++rg) {
        float q0 = 0.f, q1 = 0.f, q2 = 0.f, q3 = 0.f;
#pragma unroll
        for (int nt = 0; nt < 8; ++nt) {
          float v = acc[mt][nt][rg];
          q0 = fmaf(v, vv[nt][0], q0);
          q1 = fmaf(v, vv[nt][1], q1);
          q2 = fmaf(v, vv[nt][2], q2);
          q3 = fmaf(v, vv[nt][3], q3);
        }
#pragma unroll
        for (int off = 1; off < 16; off <<= 1) {
          q0 += __shfl_xor(q0, off, 64);
          q1 += __shfl_xor(q1, off, 64);
          q2 += __shfl_xor(q2, off, 64);
          q3 += __shfl_xor(q3, off, 64);
        }
        int r = row0 + wm + mt * 16 + lq * 4 + rg;
        if (l15 == 0 && r < M)
          *(float4*)&aldOut[(size_t)r * 4] = make_float4(q0, q1, q2, q3);
      }
  }
  // repack bf16 via LDS (swizzled) -> coalesced global stores
  __syncthreads();
#pragma unroll
  for (int mt = 0; mt < 2; ++mt)
#pragma unroll
    for (int nt = 0; nt < 8; ++nt)
#pragma unroll
      for (int rg = 0; rg < 4; ++rg) {
        int r = wm + mt * 16 + lq * 4 + rg;
        int c = (nt << 4) + l15;
        *(ushort*)(sA + ((r << 8) + ((c << 1) ^ ((r & 7) << 4)))) =
            f2bf(acc[mt][nt][rg]);
      }
  __syncthreads();
#pragma unroll
  for (int i = 0; i < 8; ++i) {
    int l = (tid + i * 256) << 4;
    int rl = l >> 8;
    if (row0 + rl < M)
      *(uint4*)((char*)Cb + (size_t)row0 * 256 + l) =
          *(const uint4*)(sA + (l ^ ((rl & 7) << 4)));
  }
}

// ---- counting sort of edges by dst ----------------------------------------
__global__ void hist_k(const int* __restrict__ dst, int* __restrict__ cnt, int E) {
  int e = blockIdx.x * blockDim.x + threadIdx.x;
  if (e < E) atomicAdd(&cnt[dst[e]], 1);
}

__global__ __launch_bounds__(256) void scanA_k(const int* __restrict__ cnt,
                                               int* __restrict__ offs,
                                               int* __restrict__ sums, int n) {
  __shared__ int ts[256];
  int tid = threadIdx.x;
  int base = blockIdx.x * 4096 + tid * 16;
  int v[16];
  int s = 0;
#pragma unroll
  for (int i = 0; i < 16; ++i) {
    v[i] = (base + i < n) ? cnt[base + i] : 0;
    s += v[i];
  }
  ts[tid] = s;
  __syncthreads();
  for (int off = 1; off < 256; off <<= 1) {
    int t = (tid >= off) ? ts[tid - off] : 0;
    __syncthreads();
    ts[tid] += t;
    __syncthreads();
  }
  int run = ts[tid] - s;
#pragma unroll
  for (int i = 0; i < 16; ++i) {
    if (base + i < n) offs[base + i] = run;
    run += v[i];
  }
  if (tid == 255) sums[blockIdx.x] = ts[255];
}

__global__ void scanB_k(int* __restrict__ sums, int nchunk) {
  if (threadIdx.x == 0) {
    int acc = 0;
    for (int i = 0; i < nchunk; ++i) {
      int t = sums[i];
      sums[i] = acc;
      acc += t;
    }
    sums[nchunk] = acc;
  }
}

__global__ void scanC_k(int* __restrict__ offs, const int* __restrict__ sums, int n) {
  int i = blockIdx.x * blockDim.x + threadIdx.x;
  if (i < n) offs[i] += sums[i >> 12];
  if (i == 0) offs[n] = sums[(n + 4095) >> 12];
}

__global__ void scatter_k(const int* __restrict__ src, const int* __restrict__ dst,
                          const int* __restrict__ offs, int* __restrict__ cur,
                          int* __restrict__ ssrc, int E) {
  int e = blockIdx.x * blockDim.x + threadIdx.x;
  if (e < E) {
    int d = dst[e];
    int pos = offs[d] + atomicAdd(&cur[d], 1);
    ssrc[pos] = src[e];
  }
}

// ---- per-dst softmax aggregation (bf16 hs) + bias + ELU -------------------
__global__ __launch_bounds__(256) void gat_agg_k(const ushort* __restrict__ hs,
    const float* __restrict__ als, const float* __restrict__ ald,
    const int* __restrict__ offs, const int* __restrict__ ssrc,
    const float* __restrict__ bias, float* __restrict__ out,
    ushort* __restrict__ outB, int Ndst,
    const float* __restrict__ Vald, float* __restrict__ aldOut) {
  const int lane = threadIdx.x & 63;
  const int n = (blockIdx.x * 256 + threadIdx.x) >> 6;
  if (n >= Ndst) return;
  const int h = lane >> 4;
  const int j = lane & 15;
  const int b = lane & 48;
  const uint* hsu = (const uint*)hs;
  const float ad = ald[(size_t)n * 4 + h];
  const int i0 = offs[n], i1 = offs[n + 1];
  const int deg = i1 - i0;
  float m_run = -INFINITY, den = 0.f, acc0 = 0.f, acc1 = 0.f;
  for (int chunk = 0; chunk < deg; chunk += 16) {
    const int cnt = min(16, deg - chunk);
    const int idx = i0 + chunk + ((j < cnt) ? j : (cnt - 1));
    const int sv = ssrc[idx];
    float e = als[(size_t)sv * 4 + h] + ad;
    e = (e > 0.f) ? e : 0.2f * e;
    if (j >= cnt) e = -INFINITY;
    float mc = e;
    mc = fmaxf(mc, __shfl_xor(mc, 1, 64));
    mc = fmaxf(mc, __shfl_xor(mc, 2, 64));
    mc = fmaxf(mc, __shfl_xor(mc, 4, 64));
    mc = fmaxf(mc, __shfl_xor(mc, 8, 64));
    const float mn = fmaxf(m_run, mc);
    const float p = __expf(e - mn);
    const float sc = __expf(m_run - mn);
    float dc = p;
    dc += __shfl_xor(dc, 1, 64);
    dc += __shfl_xor(dc, 2, 64);
    dc += __shfl_xor(dc, 4, 64);
    dc += __shfl_xor(dc, 8, 64);
    den = den * sc + dc;
    acc0 *= sc;
    acc1 *= sc;
    m_run = mn;
    int jj = 0;
    for (; jj + 4 <= cnt; jj += 4) {
      int s0 = __shfl(sv, b + jj, 64);
      int s1 = __shfl(sv, b + jj + 1, 64);
      int s2 = __shfl(sv, b + jj + 2, 64);
      int s3 = __shfl(sv, b + jj + 3, 64);
      float q0 = __shfl(p, b + jj, 64);
      float q1 = __shfl(p, b + jj + 1, 64);
      float q2 = __shfl(p, b + jj + 2, 64);
      float q3 = __shfl(p, b + jj + 3, 64);
      uint u0 = hsu[(size_t)s0 * 64 + lane];
      uint u1 = hsu[(size_t)s1 * 64 + lane];
      uint u2 = hsu[(size_t)s2 * 64 + lane];
      uint u3 = hsu[(size_t)s3 * 64 + lane];
      acc0 = fmaf(q0, bfl(u0), acc0); acc1 = fmaf(q0, bfh(u0), acc1);
      acc0 = fmaf(q1, bfl(u1), acc0); acc1 = fmaf(q1, bfh(u1), acc1);
      acc0 = fmaf(q2, bfl(u2), acc0); acc1 = fmaf(q2, bfh(u2), acc1);
      acc0 = fmaf(q3, bfl(u3), acc0); acc1 = fmaf(q3, bfh(u3), acc1);
    }
    for (; jj < cnt; ++jj) {
      int s0 = __shfl(sv, b + jj, 64);
      float q0 = __shfl(p, b + jj, 64);
      uint u0 = hsu[(size_t)s0 * 64 + lane];
      acc0 = fmaf(q0, bfl(u0), acc0);
      acc1 = fmaf(q0, bfh(u0), acc1);
    }
  }
  const float inv = 1.f / (den + 1e-16f);
  float r0 = acc0 * inv + bias[2 * lane];
  float r1 = acc1 * inv + bias[2 * lane + 1];
  r0 = (r0 > 0.f) ? r0 : expm1f(r0);
  r1 = (r1 > 0.f) ? r1 : expm1f(r1);
  *(float2*)&out[(size_t)n * 128 + 2 * lane] = make_float2(r0, r1);
  if (outB)
    ((uint*)outB)[(size_t)n * 64 + lane] = (uint)f2bf(r0) | ((uint)f2bf(r1) << 16);
  if (Vald) {
    const float4 w0 = *(const float4*)&Vald[(2 * lane) * 4];
    const float4 w1 = *(const float4*)&Vald[(2 * lane + 1) * 4];
    float t0 = fmaf(r0, w0.x, r1 * w1.x);
    float t1 = fmaf(r0, w0.y, r1 * w1.y);
    float t2 = fmaf(r0, w0.z, r1 * w1.z);
    float t3 = fmaf(r0, w0.w, r1 * w1.w);
#pragma unroll
    for (int off = 1; off < 64; off <<= 1) {
      t0 += __shfl_xor(t0, off, 64);
      t1 += __shfl_xor(t1, off, 64);
      t2 += __shfl_xor(t2, off, 64);
      t3 += __shfl_xor(t3, off, 64);
    }
    if (lane == 0)
      *(float4*)&aldOut[(size_t)n * 4] = make_float4(t0, t1, t2, t3);
  }
}

// ---- V[k,h] folds for the 4 dst attention vectors -------------------------
__global__ void vfold4_k(const float* __restrict__ Wem, const float* __restrict__ aem,
                         const float* __restrict__ Wme, const float* __restrict__ ame,
                         float* __restrict__ Vbase) {
  int idx = blockIdx.x;
  int layer = idx >> 1, et = idx & 1;
  const float* W = (et ? Wme : Wem) + layer * 16384;
  const float* a = (et ? ame : aem) + layer * 128;
  float* V = Vbase + idx * 512;
  int t = threadIdx.x;  // 512
  int k = t >> 2, h = t & 3;
  float s = 0.f;
#pragma unroll
  for (int d = 0; d < 32; ++d) s += W[k * 128 + h * 32 + d] * a[h * 32 + d];
  V[k * 4 + h] = s;
}

// ---- fused regressor tail: pred = relu(h1(bf16)@W2+b2) @ W3 + b3 ----------
__global__ __launch_bounds__(256) void regfuse_k(const ushort* __restrict__ h1,
    const float* __restrict__ W2, const float* __restrict__ b2,
    const float* __restrict__ W3, const float* __restrict__ b3,
    float* __restrict__ pred, int M) {
  __shared__ float X[64][132];
  const int tid = threadIdx.x;
  const int row0 = blockIdx.x * 64;
#pragma unroll
  for (int i = 0; i < 4; ++i) {
    int q = tid + i * 256;
    int r = q >> 4, c8 = (q & 15) << 3;
    uint4 v = make_uint4(0, 0, 0, 0);
    if (row0 + r < M) v = *(const uint4*)&h1[(size_t)(row0 + r) * 128 + c8];
    X[r][c8 + 0] = bfl(v.x); X[r][c8 + 1] = bfh(v.x);
    X[r][c8 + 2] = bfl(v.y); X[r][c8 + 3] = bfh(v.y);
    X[r][c8 + 4] = bfl(v.z); X[r][c8 + 5] = bfh(v.z);
    X[r][c8 + 6] = bfl(v.w); X[r][c8 + 7] = bfh(v.w);
  }
  __syncthreads();
  const int cg = tid & 15, rq = tid >> 4;
  const int c0 = cg * 4;
  float acc[4][4];
#pragma unroll
  for (int s = 0; s < 4; ++s)
#pragma unroll
    for (int j = 0; j < 4; ++j) acc[s][j] = 0.f;
#pragma unroll 4
  for (int k = 0; k < 128; ++k) {
    float xv[4] = {X[rq][k], X[rq + 16][k], X[rq + 32][k], X[rq + 48][k]};
    float4 w = *(const float4*)&W2[k * 64 + c0];
#pragma unroll
    for (int s = 0; s < 4; ++s) {
      acc[s][0] = fmaf(xv[s], w.x, acc[s][0]);
      acc[s][1] = fmaf(xv[s], w.y, acc[s][1]);
      acc[s][2] = fmaf(xv[s], w.z, acc[s][2]);
      acc[s][3] = fmaf(xv[s], w.w, acc[s][3]);
    }
  }
  float4 bq = *(const float4*)&b2[c0];
  float4 w3 = *(const float4*)&W3[c0];
  float bb[4] = {bq.x, bq.y, bq.z, bq.w};
  float ww[4] = {w3.x, w3.y, w3.z, w3.w};
#pragma unroll
  for (int s = 0; s < 4; ++s) {
    float v = 0.f;
#pragma unroll
    for (int j = 0; j < 4; ++j) v = fmaf(fmaxf(acc[s][j] + bb[j], 0.f), ww[j], v);
    v += __shfl_xor(v, 1, 64);
    v += __shfl_xor(v, 2, 64);
    v += __shfl_xor(v, 4, 64);
    v += __shfl_xor(v, 8, 64);
    int r = row0 + rq + 16 * s;
    if (cg == 0 && r < M) pred[r] = v + b3[0];
  }
}

extern "C" void kernel_launch(void* const* d_in, const int* in_sizes, int n_in,
                              void* d_out, int out_size, void* d_ws, size_t ws_size,
                              hipStream_t stream) {
  const float* x_exp   = (const float*)d_in[0];
  const float* x_mat   = (const float*)d_in[1];
  const int*   ei_em   = (const int*)d_in[2];
  const int*   ei_me   = (const int*)d_in[3];
  const float* Win_exp = (const float*)d_in[4];
  const float* bin_exp = (const float*)d_in[5];
  const float* Win_mat = (const float*)d_in[6];
  const float* bin_mat = (const float*)d_in[7];
  const float* Wsrc_em = (const float*)d_in[8];
  const float* Wdst_em = (const float*)d_in[9];
  const float* asrc_em = (const float*)d_in[10];
  const float* adst_em = (const float*)d_in[11];
  const float* b_em    = (const float*)d_in[12];
  const float* Wsrc_me = (const float*)d_in[13];
  const float* Wdst_me = (const float*)d_in[14];
  const float* asrc_me = (const float*)d_in[15];
  const float* adst_me = (const float*)d_in[16];
  const float* b_me    = (const float*)d_in[17];
  const float* Wr1     = (const float*)d_in[18];
  const float* br1     = (const float*)d_in[19];
  const float* Wr2     = (const float*)d_in[20];
  const float* br2     = (const float*)d_in[21];
  const float* Wr3     = (const float*)d_in[22];
  const float* br3     = (const float*)d_in[23];

  float* pred = (float*)d_out;
  float* heO  = pred + NE_N;                 // final he (fp32)
  float* hmO  = heO + (size_t)NE_N * 128;    // final hm (fp32)

  ushort* bufA = (ushort*)d_ws;                       // 12.8MB bf16 buffers
  ushort* bufB = bufA + (size_t)6400000;
  ushort* bufC = bufB + (size_t)6400000;
  ushort* Wt   = bufC + (size_t)6400000;              // 7 x 16384 bf16
  float*  als  = (float*)(Wt + 7 * 16384);
  float*  aldE = als + 200000;
  float*  aldM = aldE + 200000;
  float*  Vb   = aldM + 200000;                       // 4 x 512
  int*    sums = (int*)(Vb + 2048);
  int* offs_em = sums + 80;
  int* cur_em  = offs_em + (NM_N + 1);
  int* ssrc_em = cur_em + NM_N;
  int* offs_me = ssrc_em + NEDGE;
  int* cur_me  = offs_me + (NE_N + 1);
  int* ssrc_me = cur_me + NE_N;

  const int* se = ei_em;
  const int* de = ei_em + NEDGE;
  const int* sm = ei_me;
  const int* dm = ei_me + NEDGE;

  const int gE = (NEDGE + 255) / 256;
  const int gWave = (NE_N + 3) / 4;
  const int gGemm = (NE_N + 127) / 128;
  const int gCast = (800000 + 255) / 256;
  const int nChunkM = (NM_N + 4095) / 4096;
  const int nChunkE = (NE_N + 4095) / 4096;

  // ---- counting sort of both edge types by dst ----
  hipMemsetAsync(cur_em, 0, NM_N * sizeof(int), stream);
  hist_k<<<gE, 256, 0, stream>>>(de, cur_em, NEDGE);
  scanA_k<<<nChunkM, 256, 0, stream>>>(cur_em, offs_em, sums, NM_N);
  scanB_k<<<1, 64, 0, stream>>>(sums, nChunkM);
  scanC_k<<<(NM_N + 255) / 256, 256, 0, stream>>>(offs_em, sums, NM_N);
  hipMemsetAsync(cur_em, 0, NM_N * sizeof(int), stream);
  scatter_k<<<gE, 256, 0, stream>>>(se, de, offs_em, cur_em, ssrc_em, NEDGE);

  hipMemsetAsync(cur_me, 0, NE_N * sizeof(int), stream);
  hist_k<<<gE, 256, 0, stream>>>(dm, cur_me, NEDGE);
  scanA_k<<<nChunkE, 256, 0, stream>>>(cur_me, offs_me, sums, NE_N);
  scanB_k<<<1, 64, 0, stream>>>(sums, nChunkE);
  scanC_k<<<(NE_N + 255) / 256, 256, 0, stream>>>(offs_me, sums, NE_N);
  hipMemsetAsync(cur_me, 0, NE_N * sizeof(int), stream);
  scatter_k<<<gE, 256, 0, stream>>>(sm, dm, offs_me, cur_me, ssrc_me, NEDGE);

  // ---- weight prep: transpose+cast GEMM weights; fold dst attn vectors ----
  wcast_k<<<7, 256, 0, stream>>>(Win_exp, Win_mat, Wsrc_em, Wsrc_me,
                                 Wsrc_em + 16384, Wsrc_me + 16384, Wr1, Wt);
  vfold4_k<<<4, 512, 0, stream>>>(Wdst_em, adst_em, Wdst_me, adst_me, Vb);

  // ---- cast node features to bf16 ----
  cast_k<<<gCast, 256, 0, stream>>>(x_exp, bufA, 800000);
  cast_k<<<gCast, 256, 0, stream>>>(x_mat, bufB, 800000);

  // ---- input projections (bf16 out in-place) + dst-logit epilogues ----
  mgemm_k<<<gGemm, 256, 0, stream>>>(bufA, Wt, bin_exp, bufA, NE_N, 0,
                                     nullptr, nullptr, Vb + 512, aldE);  // he0; me0 ald
  mgemm_k<<<gGemm, 256, 0, stream>>>(bufB, Wt + 16384, bin_mat, bufB, NM_N, 0,
                                     nullptr, nullptr, Vb, aldM);        // hm0; em0 ald

  // ---- layer 1, conv em (src=he0, dst=mat) -> hmO, hm1=bufA ----
  mgemm_k<<<gGemm, 256, 0, stream>>>(bufA, Wt + 2 * 16384, nullptr, bufC, NE_N, 0,
                                     asrc_em, als, nullptr, nullptr);
  gat_agg_k<<<gWave, 256, 0, stream>>>(bufC, als, aldM, offs_em, ssrc_em, b_em,
                                       hmO, bufA, NM_N, Vb + 1024, aldM);

  // ---- layer 1, conv me (src=hm0, dst=exp) -> heO, he1=bufB ----
  mgemm_k<<<gGemm, 256, 0, stream>>>(bufB, Wt + 3 * 16384, nullptr, bufC, NM_N, 0,
                                     asrc_me, als, nullptr, nullptr);
  gat_agg_k<<<gWave, 256, 0, stream>>>(bufC, als, aldE, offs_me, ssrc_me, b_me,
                                       heO, bufB, NE_N, Vb + 1536, aldE);

  // ---- layer 2, conv em (src=he1) -> hmO final ----
  mgemm_k<<<gGemm, 256, 0, stream>>>(bufB, Wt + 4 * 16384, nullptr, bufC, NE_N, 0,
                                     asrc_em + 128, als, nullptr, nullptr);
  gat_agg_k<<<gWave, 256, 0, stream>>>(bufC, als, aldM, offs_em, ssrc_em,
                                       b_em + 128, hmO, nullptr, NM_N,
                                       nullptr, nullptr);

  // ---- layer 2, conv me (src=hm1=bufA) -> heO final, he2=bufB ----
  mgemm_k<<<gGemm, 256, 0, stream>>>(bufA, Wt + 5 * 16384, nullptr, bufC, NM_N, 0,
                                     asrc_me + 128, als, nullptr, nullptr);
  gat_agg_k<<<gWave, 256, 0, stream>>>(bufC, als, aldE, offs_me, ssrc_me,
                                       b_me + 128, heO, bufB, NE_N,
                                       nullptr, nullptr);

  // ---- regressor ----
  mgemm_k<<<gGemm, 256, 0, stream>>>(bufB, Wt + 6 * 16384, br1, bufA, NE_N, 1,
                                     nullptr, nullptr, nullptr, nullptr);
  regfuse_k<<<(NE_N + 63) / 64, 256, 0, stream>>>(bufA, Wr2, br2, Wr3, br3,
                                                  pred, NE_N);
}